// Round 5
// baseline (100.228 us; speedup 1.0000x reference)
//
#include <hip/hip_runtime.h>

typedef _Float16 half8 __attribute__((ext_vector_type(8)));
typedef _Float16 half4 __attribute__((ext_vector_type(4)));
typedef float f32x4 __attribute__((ext_vector_type(4)));

#define MFMA_F16(A, B, C) __builtin_amdgcn_mfma_f32_16x16x32_f16(A, B, C, 0, 0, 0)

#define NN 200000

// RNE float->fp16 x8
__device__ __forceinline__ half8 cvt8(const float* p) {
  half8 a;
#pragma unroll
  for (int e = 0; e < 8; ++e) a[e] = (_Float16)p[e];
  return a;
}

// ---------------- Kernel 1: encoder  x_enc = fp16(x @ Wenc^T + benc) ----------------
// 256 rows/block (64/wave, 4 M-tiles). A = Wenc frags (LDS-staged once/block),
// B = x frags, D = [hid][node] -> 8B vectorized stores. All 32 A-loads hoisted
// per wave (latency-bound fix: ~4KB in flight per CU).
__global__ __launch_bounds__(256, 2) void k_enc(const float* __restrict__ x,
                                                const float* __restrict__ Wenc,
                                                const float* __restrict__ benc,
                                                _Float16* __restrict__ xenc) {
  __shared__ _Float16 wlds[16 * 64 * 8];  // frag-packed fp16 Wenc, 16 KB

  const int tid = threadIdx.x;
  const int lane = tid & 63, wv = tid >> 6;
  const int r = lane & 15, g = lane >> 4;

  // stage Wenc -> frag-packed fp16 LDS (dwordx4 reads, 8B LDS writes)
  for (int i4 = tid; i4 < 2048; i4 += 256) {
    int idx = i4 * 4;
    f32x4 v = *(const f32x4*)(Wenc + idx);
    int j = idx >> 7, k = idx & 127;
    int tile = (j >> 4) * 4 + (k >> 5);
    int ln = ((k >> 3) & 3) * 16 + (j & 15);
    half4 h;
    h[0] = (_Float16)v[0]; h[1] = (_Float16)v[1];
    h[2] = (_Float16)v[2]; h[3] = (_Float16)v[3];
    *(half4*)&wlds[(tile * 64 + ln) * 8 + (k & 7)] = h;
  }
  __syncthreads();

  // W fragments (A-operand): 16 half8 = 64 VGPR, reused for 4 M-tiles
  half8 W[4][4];
#pragma unroll
  for (int jt = 0; jt < 4; ++jt)
#pragma unroll
    for (int kt = 0; kt < 4; ++kt)
      W[jt][kt] = *(const half8*)&wlds[((jt * 4 + kt) * 64 + lane) * 8];

  // bias per-lane: D row = hid = jt*16 + g*4 + rr
  float bb[4][4];
#pragma unroll
  for (int jt = 0; jt < 4; ++jt)
#pragma unroll
    for (int rr = 0; rr < 4; ++rr) bb[jt][rr] = benc[jt * 16 + g * 4 + rr];

  const int base = blockIdx.x * 256 + wv * 64;

  // hoist ALL A-side (x) loads: 32 dwordx4 in flight
  f32x4 xr[4][4][2];
#pragma unroll
  for (int mt = 0; mt < 4; ++mt) {
    int arow = base + mt * 16 + r;
    if (arow >= NN) arow = NN - 1;  // clamp loads; stores guarded below
    const float* rowp = x + (size_t)arow * 128;
#pragma unroll
    for (int kt = 0; kt < 4; ++kt) {
      const f32x4* p = (const f32x4*)(rowp + kt * 32 + g * 8);
      xr[mt][kt][0] = p[0];
      xr[mt][kt][1] = p[1];
    }
  }

#pragma unroll
  for (int mt = 0; mt < 4; ++mt) {
    f32x4 acc[4];
#pragma unroll
    for (int jt = 0; jt < 4; ++jt)
      acc[jt] = (f32x4){bb[jt][0], bb[jt][1], bb[jt][2], bb[jt][3]};

#pragma unroll
    for (int kt = 0; kt < 4; ++kt) {
      half8 a;
#pragma unroll
      for (int e = 0; e < 4; ++e) {
        a[e] = (_Float16)xr[mt][kt][0][e];
        a[4 + e] = (_Float16)xr[mt][kt][1][e];
      }
#pragma unroll
      for (int jt = 0; jt < 4; ++jt)
        acc[jt] = MFMA_F16(W[jt][kt], a, acc[jt]);  // A=W, B=x -> D=[hid][node]
    }

    // D: col = node = r, row = hid = g*4+rr  -> lane owns 4 consecutive hid of node
    int node = base + mt * 16 + r;
    if (node < NN) {
#pragma unroll
      for (int jt = 0; jt < 4; ++jt) {
        half4 o;
        o[0] = (_Float16)acc[jt][0]; o[1] = (_Float16)acc[jt][1];
        o[2] = (_Float16)acc[jt][2]; o[3] = (_Float16)acc[jt][3];
        *(half4*)&xenc[(size_t)node * 64 + jt * 16 + g * 4] = o;  // 8B store
      }
    }
  }
}

// ---------------- Kernel 2: GRU over walks + per-graph mean pooling ----------------
// 1 wave = 1 graph = 16 walks. grid 256 x 256thr. All weights in registers.
__global__ __launch_bounds__(256, 1) void k_gru(const _Float16* __restrict__ xenc,
                                                const int* __restrict__ walks,
                                                const float* __restrict__ Wih,
                                                const float* __restrict__ Whh,
                                                const float* __restrict__ bih,
                                                const float* __restrict__ bhh,
                                                float* __restrict__ genc) {
  __shared__ _Float16 h_lds[4][16 * 64];  // per-wave h transpose buffer (8 KB)
  __shared__ int ids[4][256];             // per-wave walk node ids, transposed (4 KB)

  const int tid = threadIdx.x;
  const int lane = tid & 63, wv = tid >> 6;
  const int r = lane & 15, g = lane >> 4;

  // W_ih and W_hh fragments in registers (48 half8 = 192 VGPR), reused 16 steps
  half8 Bih[12][2], Bhh[12][2];
#pragma unroll
  for (int jt = 0; jt < 12; ++jt)
#pragma unroll
    for (int kt = 0; kt < 2; ++kt) {
      Bih[jt][kt] = cvt8(Wih + (jt * 16 + r) * 64 + kt * 32 + g * 8);
      Bhh[jt][kt] = cvt8(Whh + (jt * 16 + r) * 64 + kt * 32 + g * 8);
    }

  // per-lane biases (indexed by output col = jt*16 + r)
  float brz[8], bin4[4], bhn4[4];
#pragma unroll
  for (int jt = 0; jt < 8; ++jt) brz[jt] = bih[jt * 16 + r] + bhh[jt * 16 + r];
#pragma unroll
  for (int jt = 0; jt < 4; ++jt) {
    bin4[jt] = bih[128 + jt * 16 + r];
    bhn4[jt] = bhh[128 + jt * 16 + r];
  }

  const int gph = blockIdx.x * 4 + wv;  // graph id == wave id
  {
    const int* wp = walks + gph * 256;
    int4 v = *(const int4*)(wp + lane * 4);
    int vals[4] = {v.x, v.y, v.z, v.w};
#pragma unroll
    for (int i = 0; i < 4; ++i) {
      int m = lane * 4 + i;  // m = w*16 + t
      ids[wv][(m & 15) * 16 + (m >> 4)] = vals[i];
    }
  }

  for (int i = lane; i < 16 * 64; i += 64) h_lds[wv][i] = (_Float16)0.f;
  // no __syncthreads needed: all LDS traffic is wave-private

  f32x4 h[4];
#pragma unroll
  for (int jt = 0; jt < 4; ++jt) h[jt] = (f32x4){0.f, 0.f, 0.f, 0.f};

  char* hbase = (char*)&h_lds[wv][0];
  const int swz = (r & 7) << 4;

  // prefetch step 0 gather
  int nid0 = ids[wv][r];
  const _Float16* xp0 = xenc + (size_t)nid0 * 64 + g * 8;
  half8 Ax0 = *(const half8*)xp0;
  half8 Ax1 = *(const half8*)(xp0 + 32);

#pragma unroll 2
  for (int t = 0; t < 16; ++t) {
    // prefetch step t+1 gather (ids known upfront; hides L2/L3 latency)
    int tn = (t + 1) & 15;
    int nid = ids[wv][tn * 16 + r];
    const _Float16* xp = xenc + (size_t)nid * 64 + g * 8;
    half8 Nx0 = *(const half8*)xp;
    half8 Nx1 = *(const half8*)(xp + 32);

    // A_h fragments from swizzled LDS (row = walk r)
    half8 Ah0 = *(const half8*)(hbase + ((r * 128 + g * 16) ^ swz));
    half8 Ah1 = *(const half8*)(hbase + ((r * 128 + 64 + g * 16) ^ swz));

    f32x4 aRZ[8], aIN[4], aHN[4];
#pragma unroll
    for (int jt = 0; jt < 8; ++jt) aRZ[jt] = (f32x4){brz[jt], brz[jt], brz[jt], brz[jt]};
#pragma unroll
    for (int jt = 0; jt < 4; ++jt) {
      aIN[jt] = (f32x4){bin4[jt], bin4[jt], bin4[jt], bin4[jt]};
      aHN[jt] = (f32x4){bhn4[jt], bhn4[jt], bhn4[jt], bhn4[jt]};
    }

    // gi = xt @ W_ih^T first (Ax ready from prefetch)
#pragma unroll
    for (int jt = 0; jt < 8; ++jt) {
      aRZ[jt] = MFMA_F16(Ax0, Bih[jt][0], aRZ[jt]);
      aRZ[jt] = MFMA_F16(Ax1, Bih[jt][1], aRZ[jt]);
    }
#pragma unroll
    for (int jt = 0; jt < 4; ++jt) {
      aIN[jt] = MFMA_F16(Ax0, Bih[8 + jt][0], aIN[jt]);
      aIN[jt] = MFMA_F16(Ax1, Bih[8 + jt][1], aIN[jt]);
    }

    // gh = h @ W_hh^T
#pragma unroll
    for (int jt = 0; jt < 8; ++jt) {
      aRZ[jt] = MFMA_F16(Ah0, Bhh[jt][0], aRZ[jt]);
      aRZ[jt] = MFMA_F16(Ah1, Bhh[jt][1], aRZ[jt]);
    }
#pragma unroll
    for (int jt = 0; jt < 4; ++jt) {
      aHN[jt] = MFMA_F16(Ah0, Bhh[8 + jt][0], aHN[jt]);
      aHN[jt] = MFMA_F16(Ah1, Bhh[8 + jt][1], aHN[jt]);
    }

    // gates (division-free: raw v_rcp; tanh = 1 - 2*rcp(e2+1), saturates correctly)
#pragma unroll
    for (int jt = 0; jt < 4; ++jt)
#pragma unroll
      for (int rr = 0; rr < 4; ++rr) {
        float pr = aRZ[jt][rr];
        float pz = aRZ[4 + jt][rr];
        float rg = __builtin_amdgcn_rcpf(1.f + __expf(-pr));
        float zg = __builtin_amdgcn_rcpf(1.f + __expf(-pz));
        float pn = aIN[jt][rr] + rg * aHN[jt][rr];
        float e2 = __expf(2.f * pn);
        float nn = 1.f - 2.f * __builtin_amdgcn_rcpf(e2 + 1.f);
        h[jt][rr] = (1.f - zg) * nn + zg * h[jt][rr];
      }

    // write h (fp16) back to swizzled LDS for next step's A-fragments
    if (t < 15) {
#pragma unroll
      for (int jt = 0; jt < 4; ++jt)
#pragma unroll
        for (int rr = 0; rr < 4; ++rr) {
          int row = g * 4 + rr;
          int byte = (row * 128 + (jt * 16 + r) * 2) ^ ((row & 7) << 4);
          *(_Float16*)(hbase + byte) = (_Float16)h[jt][rr];
        }
    }

    Ax0 = Nx0;
    Ax1 = Nx1;
  }

  // fused segment-mean over the wave's 16 walks
#pragma unroll
  for (int jt = 0; jt < 4; ++jt) {
    float s = h[jt][0] + h[jt][1] + h[jt][2] + h[jt][3];
    s += __shfl_xor(s, 16);
    s += __shfl_xor(s, 32);
    if (g == 0) genc[gph * 64 + jt * 16 + r] = s * 0.0625f;
  }
}

// ---------------- Kernel 3: BN batch stats -> scale/shift ----------------
__global__ __launch_bounds__(1024) void k_stats(const float* __restrict__ genc,
                                                const float* __restrict__ gamma,
                                                const float* __restrict__ beta,
                                                float* __restrict__ ss) {
  __shared__ float sum_s[16][64], sq_s[16][64];
  int j = threadIdx.x & 63, grp = threadIdx.x >> 6;
  float s = 0.f, q = 0.f;
#pragma unroll 4
  for (int rr = 0; rr < 64; ++rr) {
    float v = genc[(grp * 64 + rr) * 64 + j];
    s += v;
    q += v * v;
  }
  sum_s[grp][j] = s;
  sq_s[grp][j] = q;
  __syncthreads();
  if (grp == 0) {
    float S = 0.f, Q = 0.f;
#pragma unroll
    for (int k = 0; k < 16; ++k) {
      S += sum_s[k][j];
      Q += sq_s[k][j];
    }
    float mean = S * (1.f / 1024.f);
    float var = Q * (1.f / 1024.f) - mean * mean;
    float rstd = rsqrtf(var + 1e-5f);
    float sc = gamma[j] * rstd;
    ss[j] = sc;
    ss[64 + j] = beta[j] - mean * sc;
  }
}

// ---------------- Kernel 4: BN apply + MLP + log_softmax ----------------
__global__ __launch_bounds__(256, 1) void k_mlp(const float* __restrict__ genc,
                                                const float* __restrict__ ss,
                                                const float* __restrict__ W1,
                                                const float* __restrict__ b1,
                                                const float* __restrict__ W2,
                                                const float* __restrict__ b2,
                                                float* __restrict__ out) {
  __shared__ float w1[32 * 64], w2[10 * 32], bb1[32], bb2[10], sc[64], sh[64];
  const int tid = threadIdx.x;
  for (int i = tid; i < 32 * 64; i += 256) w1[i] = W1[i];
  for (int i = tid; i < 10 * 32; i += 256) w2[i] = W2[i];
  if (tid < 32) bb1[tid] = b1[tid];
  if (tid >= 32 && tid < 42) bb2[tid - 32] = b2[tid - 32];
  if (tid >= 64 && tid < 128) sc[tid - 64] = ss[tid - 64];
  if (tid >= 128 && tid < 192) sh[tid - 128] = ss[64 + tid - 128];
  __syncthreads();

  const int row = blockIdx.x * 256 + tid;
  float gn[64];
  const f32x4* gp = (const f32x4*)(genc + row * 64);
#pragma unroll
  for (int jq = 0; jq < 16; ++jq) {
    f32x4 v = gp[jq];
#pragma unroll
    for (int e = 0; e < 4; ++e) gn[jq * 4 + e] = v[e] * sc[jq * 4 + e] + sh[jq * 4 + e];
  }

  float h1[32];
#pragma unroll
  for (int i = 0; i < 32; ++i) {
    float a = bb1[i];
#pragma unroll
    for (int j = 0; j < 64; ++j) a += w1[i * 64 + j] * gn[j];
    h1[i] = fmaxf(a, 0.f);
  }

  float lg[10];
  float mx = -1e30f;
#pragma unroll
  for (int c = 0; c < 10; ++c) {
    float a = bb2[c];
#pragma unroll
    for (int i = 0; i < 32; ++i) a += w2[c * 32 + i] * h1[i];
    lg[c] = a;
    mx = fmaxf(mx, a);
  }
  float se = 0.f;
#pragma unroll
  for (int c = 0; c < 10; ++c) se += __expf(lg[c] - mx);
  float lse = mx + __logf(se);
#pragma unroll
  for (int c = 0; c < 10; ++c) out[row * 10 + c] = lg[c] - lse;
}

// ---------------- host launcher ----------------
extern "C" void kernel_launch(void* const* d_in, const int* in_sizes, int n_in,
                              void* d_out, int out_size, void* d_ws, size_t ws_size,
                              hipStream_t stream) {
  const float* x = (const float*)d_in[0];
  const int* walks = (const int*)d_in[1];
  /* d_in[2] walk_batch: repeat(arange(1024),16) -> wave==graph */
  const float* Wenc = (const float*)d_in[3];
  const float* benc = (const float*)d_in[4];
  const float* Wih = (const float*)d_in[5];
  const float* Whh = (const float*)d_in[6];
  const float* bih = (const float*)d_in[7];
  const float* bhh = (const float*)d_in[8];
  const float* gamma = (const float*)d_in[9];
  const float* beta = (const float*)d_in[10];
  const float* W1 = (const float*)d_in[11];
  const float* b1 = (const float*)d_in[12];
  const float* W2 = (const float*)d_in[13];
  const float* b2 = (const float*)d_in[14];
  float* out = (float*)d_out;

  char* ws = (char*)d_ws;
  _Float16* xenc = (_Float16*)ws;                 // 25,600,000 B
  float* genc = (float*)(ws + 25600000);          // 262,144 B
  float* ss = (float*)(ws + 25600000 + 262144);   // 512 B

  k_enc<<<dim3(782), dim3(256), 0, stream>>>(x, Wenc, benc, xenc);
  k_gru<<<dim3(256), dim3(256), 0, stream>>>(xenc, walks, Wih, Whh, bih, bhh, genc);
  k_stats<<<dim3(1), dim3(1024), 0, stream>>>(genc, gamma, beta, ss);
  k_mlp<<<dim3(4), dim3(256), 0, stream>>>(genc, ss, W1, b1, W2, b2, out);
}